// Round 14
// baseline (55.970 us; speedup 1.0000x reference)
//
#include <hip/hip_runtime.h>
#include <hip/hip_fp16.h>

// SSIM loss — round 14: global_load_lds staging (no VGPR round-trip).
// P1: DMA-stage f32 (a,b) halo planes (42x80 each) linearly into LDS via
//     __builtin_amdgcn_global_load_lds width=16; per-lane PRE-SWIZZLED global
//     source (byte-bit4 ^= (row>>1)&1) so P2's ds_read_b128 is conflict-free
//     (T21: swizzle source + read, LDS stays linear). Boundary blocks
//     pre-zero the stage (disjoint from DMA writes, barrier-ordered).
// P2: 336 items, 1/thread: 12 ds_read_b128 + f16 convert + 176 hfma2 ->
//     merged H4 plane {(sa,sb),(qsum,sab)}. P3: v-conv 4 rows/thread.
// 512 threads, LDS ~49.7KB -> 3 blocks/CU (24 waves, 75% ceiling).

#define IMGH 512
#define IMGW 512
#define TW 64
#define TH 32
#define HRR 42            // TH + 10 h-rows
#define C1F 1.0e-4f
#define C2F 9.0e-4f
#define GX 8
#define GY 16
#define GZ 48
#define NBLOCKS (GX * GY * GZ)   // 6144
#define NPIX (16 * 3 * 512 * 512)

#define PLANE_W 3360      // 42*80 f32 words per plane
#define STAGE_W 6912      // 2 planes + 768B slack (27 x 1024B issues)
#define STAGE_BYTES 26880 // valid staged bytes

// Gaussian weights, sigma=1.5, ws=11 (validated r1-r13).
#define W0 0.0010283818f
#define W1 0.0075987503f
#define W2 0.0360007547f
#define W3 0.1093606960f
#define W4 0.2130055367f
#define W5 0.2660117184f

struct alignas(8) H4 { __half2 ab; __half2 qc; };  // (sa,sb) , (saa+sbb, sab)

static __device__ __forceinline__ __half2 pkrtz(float a, float b) {
    auto r = __builtin_amdgcn_cvt_pkrtz(a, b);   // __fp16 ext_vector(2)
    return *reinterpret_cast<__half2*>(&r);
}

static __device__ __forceinline__ void gload16(const void* g, void* l) {
    __builtin_amdgcn_global_load_lds(
        (const __attribute__((address_space(1))) void*)g,
        (__attribute__((address_space(3))) void*)l, 16, 0, 0);
}

__global__ __launch_bounds__(512, 4)
void ssim_tile(const float* __restrict__ img1, const float* __restrict__ img2,
               float* __restrict__ partials) {
    __shared__ float stage[STAGE_W];        // 27,648 B : A plane | B plane
    __shared__ H4 sPm[HRR][64];             // 21,504 B, stride 512B
    __shared__ float wsum[8];

    const float W[11] = {W0, W1, W2, W3, W4, W5, W4, W3, W2, W1, W0};
    __half2 wsH[11];      // (W[i], W[i])
#pragma unroll
    for (int i = 0; i < 11; ++i) wsH[i] = __half2half2(__float2half(W[i]));

    const int tid = threadIdx.x;
    const int r0 = blockIdx.y * TH;
    const int c0 = blockIdx.x * TW;
    const size_t pbase = (size_t)blockIdx.z * (IMGH * IMGW);
    const float* a0 = img1 + pbase;
    const float* b0 = img2 + pbase;
    const bool fast = (blockIdx.x >= 1) & (blockIdx.x <= GX - 2) &
                      (blockIdx.y >= 1) & (blockIdx.y <= GY - 2);

    // ---- Phase 1: DMA-stage halo planes (pre-swizzled global source) ----
    if (!fast) {
        // zero-fill so skipped (OOB) DMA lanes read as 0 padding
        const float4 z4 = make_float4(0.f, 0.f, 0.f, 0.f);
        for (int t = tid; t < STAGE_W / 4; t += 512)
            reinterpret_cast<float4*>(stage)[t] = z4;
        __syncthreads();
    }
    {
        const int wv = tid >> 6, ln = tid & 63;
        for (int i = wv; i < 27; i += 8) {
            int o = (i << 10) + (ln << 4);          // lds byte offset
            if (o < STAGE_BYTES) {
                int plane = (o >= PLANE_W * 4) ? 1 : 0;
                int po = o - plane * (PLANE_W * 4);
                int row = (unsigned)po / 320u;      // 320B per staged row
                int ro  = po - row * 320;
                ro ^= ((row >> 1) & 1) << 4;        // stage swizzle (bit 4)
                int gr = r0 - 5 + row;
                int gc = c0 - 8 + (ro >> 2);
                if (fast || ((unsigned)gr < IMGH && (unsigned)gc < IMGW)) {
                    const float* g = (plane ? b0 : a0) + (size_t)gr * IMGW + gc;
                    gload16(g, reinterpret_cast<char*>(stage) + (i << 10));
                }
            }
        }
    }
    __syncthreads();

    // ---- Phase 2: horizontal conv, 8 out cols per item, 1 item/thread ----
    if (tid < HRR * 8) {
        const int row = tid >> 3;
        const int cg  = tid & 7;
        const int s4  = ((row >> 1) & 1) << 2;      // read-side swizzle (words)
        const float* pa = stage + row * 80 + cg * 8;
        const float* pb = pa + PLANE_W;

        float4 va[6], vb[6];
#pragma unroll
        for (int q = 0; q < 6; ++q) {
            int off = ((q << 2) ^ s4);
            va[q] = *reinterpret_cast<const float4*>(pa + off);
            vb[q] = *reinterpret_cast<const float4*>(pb + off);
        }

        __half2 AB[18], QC[18];
        auto emit = [&](int t, float a, float b) {
            AB[t] = pkrtz(a, b);
            QC[t] = pkrtz(__builtin_fmaf(a, a, b * b), a * b);
        };
        emit(0, va[0].w, vb[0].w);
#pragma unroll
        for (int g = 1; g < 6; ++g) {
            int t = 4 * g - 3;
            emit(t,     va[g].x, vb[g].x);
            emit(t + 1, va[g].y, vb[g].y);
            emit(t + 2, va[g].z, vb[g].z);
            if (g < 5) emit(t + 3, va[g].w, vb[g].w);
        }

        __half2 accAB[8], accQC[8];
        const __half2 z2 = __half2half2(__float2half(0.f));
#pragma unroll
        for (int m = 0; m < 8; ++m) { accAB[m] = z2; accQC[m] = z2; }
#pragma unroll
        for (int t = 0; t < 18; ++t) {
#pragma unroll
            for (int m = 0; m < 8; ++m) {
                int k = t - m;
                if (k >= 0 && k <= 10) {
                    accAB[m] = __hfma2(wsH[k], AB[t], accAB[m]);
                    accQC[m] = __hfma2(wsH[k], QC[t], accQC[m]);
                }
            }
        }
#pragma unroll
        for (int m = 0; m < 8; m += 2) {
            float4 st;
            reinterpret_cast<__half2*>(&st)[0] = accAB[m];
            reinterpret_cast<__half2*>(&st)[1] = accQC[m];
            reinterpret_cast<__half2*>(&st)[2] = accAB[m + 1];
            reinterpret_cast<__half2*>(&st)[3] = accQC[m + 1];
            *reinterpret_cast<float4*>(&sPm[row][8 * cg + m]) = st;
        }
    }
    __syncthreads();

    // ---- Phase 3: vertical conv, 1 col x 4 rows per thread ----
    const int col = tid & 63;
    const int rbase = (tid >> 6) * 4;      // 0,4,...,28 ; out rows rbase..+3
    const H4* pm = &sPm[rbase][col];

    __half2 mAB[4], mQC[4];
    {
        const __half2 z2 = __half2half2(__float2half(0.f));
#pragma unroll
        for (int r = 0; r < 4; ++r) { mAB[r] = z2; mQC[r] = z2; }
    }
#pragma unroll
    for (int j = 0; j < 14; ++j) {
        H4 h = pm[j * 64];                 // imm offset j*512B
#pragma unroll
        for (int r = 0; r < 4; ++r) {
            int i = j - r;
            if (i >= 0 && i <= 10) {
                mAB[r] = __hfma2(wsH[i], h.ab, mAB[r]);
                mQC[r] = __hfma2(wsH[i], h.qc, mQC[r]);
            }
        }
    }

    float lsum = 0.f;
#pragma unroll
    for (int r = 0; r < 4; ++r) {
        float2 m12 = __half22float2(mAB[r]);
        float2 qc  = __half22float2(mQC[r]);   // (E[aa]+E[bb], E[ab])
        float mu1 = m12.x, mu2 = m12.y;
        float mu11 = mu1 * mu1, mu22 = mu2 * mu2, mu12 = mu1 * mu2;
        float s12 = qc.y - mu12;
        float num = (2.f * mu12 + C1F) * (2.f * s12 + C2F);
        float den = (mu11 + mu22 + C1F) * ((qc.x - mu11 - mu22) + C2F);
        lsum += num * __builtin_amdgcn_rcpf(den);
    }

    // ---- Deterministic block reduction (8 waves) ----
#pragma unroll
    for (int off = 32; off > 0; off >>= 1) lsum += __shfl_down(lsum, off, 64);
    if ((tid & 63) == 0) wsum[tid >> 6] = lsum;
    __syncthreads();
    if (tid == 0) {
        float t = 0.f;
#pragma unroll
        for (int w = 0; w < 8; ++w) t += wsum[w];
        partials[((size_t)blockIdx.z * GY + blockIdx.y) * GX + blockIdx.x] = t;
    }
}

__global__ __launch_bounds__(1024)
void ssim_reduce(const float* __restrict__ partials, float* __restrict__ out, int n) {
    __shared__ float lds[1024];
    float s = 0.f;
    for (int i = threadIdx.x; i < n; i += 1024) s += partials[i];
    lds[threadIdx.x] = s;
    __syncthreads();
    for (int off = 512; off > 0; off >>= 1) {
        if ((int)threadIdx.x < off) lds[threadIdx.x] += lds[threadIdx.x + off];
        __syncthreads();
    }
    if (threadIdx.x == 0) out[0] = 1.f - lds[0] / (float)NPIX;
}

extern "C" void kernel_launch(void* const* d_in, const int* in_sizes, int n_in,
                              void* d_out, int out_size, void* d_ws, size_t ws_size,
                              hipStream_t stream) {
    const float* img1 = (const float*)d_in[0];
    const float* img2 = (const float*)d_in[1];
    float* out = (float*)d_out;
    float* partials = (float*)d_ws;

    dim3 grid(GX, GY, GZ);
    ssim_tile<<<grid, 512, 0, stream>>>(img1, img2, partials);
    ssim_reduce<<<1, 1024, 0, stream>>>(partials, out, NBLOCKS);
}

// Round 16
// 52.045 us; speedup vs baseline: 1.0754x; 1.0754x over previous
//
#include <hip/hip_runtime.h>
#include <hip/hip_fp16.h>

// SSIM loss — round 16: banded-conv via MFMA, weight-table OOB fix.
// r15 bug: v-pass band index went to -3 (OOB LDS read -> NaN f16 weights).
// Table now 96 entries, band center +34 -> all indices in [13,65].
// Conv-as-matmul: D[m,r] = sum_k A[m,k]*B[k,r], A = banded Gaussian,
// one mfma_f32_16x16x32_f16 per 16x16 conv tile, f32 accumulation.
// prep (global -> 4 f16 quantity planes {a,b,aa+bb,ab}) -> h-MFMA (48) ->
// v-MFMA (32; wave owns (rt,ct), 4 quantities -> lane-local SSIM) -> reduce.
// Tile 64x32, 512 thr, LDS ~52.5KB -> 3 blk/CU.

#define IMGH 512
#define IMGW 512
#define TW 64
#define TH 32
#define GX 8
#define GY 16
#define GZ 48
#define NBLOCKS (GX * GY * GZ)   // 6144
#define NPIX (16 * 3 * 512 * 512)
#define C1F 1.0e-4f
#define C2F 9.0e-4f

#define INROWS 42
#define INSTRIDE 88        // halfs/row = 176B: 16B-aligned, 2-way max banks
#define INPLANE (INROWS * INSTRIDE)   // 3696 halfs (7392B)
#define VSTRIDE 44         // halfs/col = 88B: bank step 22 words, all-distinct
#define VPLANE (64 * VSTRIDE)         // 2816 halfs (5632B)
#define WBASE 34           // band center in sWext

// Gaussian weights, sigma=1.5, ws=11 (validated r1-r14).
#define W0 0.0010283818f
#define W1 0.0075987503f
#define W2 0.0360007547f
#define W3 0.1093606960f
#define W4 0.2130055367f
#define W5 0.2660117184f

typedef _Float16 half8v __attribute__((ext_vector_type(8)));
typedef float f32x4 __attribute__((ext_vector_type(4)));

static __device__ __forceinline__ __half2 pkrtz(float a, float b) {
    auto r = __builtin_amdgcn_cvt_pkrtz(a, b);   // __fp16 ext_vector(2)
    return *reinterpret_cast<__half2*>(&r);
}

__global__ __launch_bounds__(512, 4)
void ssim_tile(const float* __restrict__ img1, const float* __restrict__ img2,
               float* __restrict__ partials) {
    __shared__ _Float16 sWext[96];          // [WBASE..WBASE+10] = W[0..10]
    __shared__ _Float16 sIn[4 * INPLANE];   // 29,568 B : a | b | aa+bb | ab
    __shared__ _Float16 sV[4 * VPLANE];     // 22,528 B : h-conv out, col-major
    __shared__ float wsum[8];

    const int tid  = threadIdx.x;
    const int lane = tid & 63;
    const int wv   = tid >> 6;
    const int r0 = blockIdx.y * TH;
    const int c0 = blockIdx.x * TW;
    const size_t pbase = (size_t)blockIdx.z * (IMGH * IMGW);
    const float* a0 = img1 + pbase;
    const float* b0 = img2 + pbase;
    const bool fast = (blockIdx.x >= 1) & (blockIdx.x <= GX - 2) &
                      (blockIdx.y >= 1) & (blockIdx.y <= GY - 2);

    // ---- weight table (tid<96): sWext[WBASE+j] = W[j], else 0 ----
    if (tid < 96) {
        const float W[11] = {W0, W1, W2, W3, W4, W5, W4, W3, W2, W1, W0};
        float w = 0.f;
#pragma unroll
        for (int j = 0; j < 11; ++j) w = (tid == WBASE + j) ? W[j] : w;
        sWext[tid] = (_Float16)w;
    }

    // ---- prep: 840 quads (42 rows x 20 col-quads) -> 4 f16 planes ----
    auto prep = [&](int qid) {
        const int row = qid / 20;
        const int cq  = qid - row * 20;
        const int gr = r0 - 5 + row;
        const int gc = c0 - 8 + 4 * cq;
        float4 va = make_float4(0.f, 0.f, 0.f, 0.f), vb = va;
        if (fast || ((unsigned)gr < IMGH && (unsigned)gc < IMGW)) {
            va = *reinterpret_cast<const float4*>(a0 + (size_t)gr * IMGW + gc);
            vb = *reinterpret_cast<const float4*>(b0 + (size_t)gr * IMGW + gc);
        }
        const int off = row * INSTRIDE + 4 * cq;   // byte = 176row+8cq, 8B ok
        auto st = [&](int plane, __half2 lo, __half2 hi) {
            uint2 u;
            u.x = *reinterpret_cast<const unsigned*>(&lo);
            u.y = *reinterpret_cast<const unsigned*>(&hi);
            *reinterpret_cast<uint2*>(&sIn[plane * INPLANE + off]) = u;
        };
        st(0, pkrtz(va.x, va.y), pkrtz(va.z, va.w));           // a
        st(1, pkrtz(vb.x, vb.y), pkrtz(vb.z, vb.w));           // b
        float q0 = __builtin_fmaf(va.x, va.x, vb.x * vb.x);
        float q1 = __builtin_fmaf(va.y, va.y, vb.y * vb.y);
        float q2 = __builtin_fmaf(va.z, va.z, vb.z * vb.z);
        float q3 = __builtin_fmaf(va.w, va.w, vb.w * vb.w);
        st(2, pkrtz(q0, q1), pkrtz(q2, q3));                   // aa+bb
        st(3, pkrtz(va.x * vb.x, va.y * vb.y),
              pkrtz(va.z * vb.z, va.w * vb.w));                // ab
    };
    prep(tid);
    if (tid < 840 - 512) prep(tid + 512);
    __syncthreads();

    // ---- A fragments from weight table ----
    // Layout (guide m89): A[M][K]: M = lane&15, K = (lane>>4)*8 + e.
    const int rt2 = wv >> 2;                   // this wave's v row-tile
    half8v Ah, Av;
    {
        const int bh = ((lane >> 4) << 3) - (lane & 15) - 3 + WBASE;  // W[k-m-3]
        const int bv = ((lane >> 4) << 3) - (lane & 15) - (rt2 ? 6 : 0) + WBASE;
#pragma unroll
        for (int e = 0; e < 8; ++e) Ah[e] = sWext[bh + e];
#pragma unroll
        for (int e = 0; e < 8; ++e) Av[e] = sWext[bv + e];
    }

    // ---- h-phase: 48 tiles, 6 per wave ----
    // Tile id -> (rt row-base {0,16,26}, ct col-tile, q plane). Out col
    // 16ct+m taps stage cols 16ct+m+3..m+13 -> A band W[k-m-3], k<=28.
#pragma unroll
    for (int i = 0; i < 6; ++i) {
        const int id = wv + (i << 3);
        const int rt = id >> 4;
        const int ct = (id >> 2) & 3;
        const int q  = id & 3;
        const int rb = (rt == 0) ? 0 : (rt == 1 ? 16 : 26);
        const int row = rb + (lane & 15);          // img h-row (N dim)
        const int colstart = 16 * ct + ((lane >> 4) << 3);
        const half8v b = *reinterpret_cast<const half8v*>(
            &sIn[q * INPLANE + row * INSTRIDE + colstart]);
        f32x4 d = {0.f, 0.f, 0.f, 0.f};
        d = __builtin_amdgcn_mfma_f32_16x16x32_f16(Ah, b, d, 0, 0, 0);
        // rt=2 tile recomputes rows 26..31 (already done by rt=1): skip them.
        if (rt < 2 || (lane & 15) >= 6) {
#pragma unroll
            for (int j = 0; j < 4; ++j) {
                const int oc = 16 * ct + ((lane >> 4) << 2) + j;  // M dim
                sV[q * VPLANE + oc * VSTRIDE + row] = (_Float16)d[j];
            }
        }
    }
    __syncthreads();

    // ---- v-phase: wave wv owns (rt2, ct2); 4 MFMA (one per quantity) ----
    // Window start w0: rt2=0 -> 0 (band W[k-m]); rt2=1 -> 10 (band W[k-m-6]).
    const int ct2 = wv & 3;
    const int w0 = rt2 ? 10 : 0;
    const int vcol = 16 * ct2 + (lane & 15);           // N dim = out col
    const int rowst = w0 + ((lane >> 4) << 3);         // K chunk start
    auto vread = [&](int q) -> half8v {
        const _Float16* p = &sV[q * VPLANE + vcol * VSTRIDE + rowst];
        union { unsigned u[4]; half8v h; } c;          // 4B-aligned b32 reads
        c.u[0] = *reinterpret_cast<const unsigned*>(p);
        c.u[1] = *reinterpret_cast<const unsigned*>(p + 2);
        c.u[2] = *reinterpret_cast<const unsigned*>(p + 4);
        c.u[3] = *reinterpret_cast<const unsigned*>(p + 6);
        return c.h;
    };
    f32x4 d0 = {0.f, 0.f, 0.f, 0.f}, d1 = d0, d2 = d0, d3 = d0;
    d0 = __builtin_amdgcn_mfma_f32_16x16x32_f16(Av, vread(0), d0, 0, 0, 0);
    d1 = __builtin_amdgcn_mfma_f32_16x16x32_f16(Av, vread(1), d1, 0, 0, 0);
    d2 = __builtin_amdgcn_mfma_f32_16x16x32_f16(Av, vread(2), d2, 0, 0, 0);
    d3 = __builtin_amdgcn_mfma_f32_16x16x32_f16(Av, vread(3), d3, 0, 0, 0);

    // ---- SSIM map, lane-local on f32 conv outputs ----
    float lsum = 0.f;
#pragma unroll
    for (int r = 0; r < 4; ++r) {
        const float mu1 = d0[r], mu2 = d1[r], S = d2[r], eab = d3[r];
        const float mu11 = mu1 * mu1, mu22 = mu2 * mu2, mu12 = mu1 * mu2;
        const float s12 = eab - mu12;
        const float num = (2.f * mu12 + C1F) * (2.f * s12 + C2F);
        const float den = (mu11 + mu22 + C1F) * ((S - mu11 - mu22) + C2F);
        lsum += num * __builtin_amdgcn_rcpf(den);
    }

    // ---- deterministic block reduction (8 waves) ----
#pragma unroll
    for (int off = 32; off > 0; off >>= 1) lsum += __shfl_down(lsum, off, 64);
    if (lane == 0) wsum[wv] = lsum;
    __syncthreads();
    if (tid == 0) {
        float t = 0.f;
#pragma unroll
        for (int w = 0; w < 8; ++w) t += wsum[w];
        partials[((size_t)blockIdx.z * GY + blockIdx.y) * GX + blockIdx.x] = t;
    }
}

__global__ __launch_bounds__(1024)
void ssim_reduce(const float* __restrict__ partials, float* __restrict__ out, int n) {
    __shared__ float lds[1024];
    float s = 0.f;
    for (int i = threadIdx.x; i < n; i += 1024) s += partials[i];
    lds[threadIdx.x] = s;
    __syncthreads();
    for (int off = 512; off > 0; off >>= 1) {
        if ((int)threadIdx.x < off) lds[threadIdx.x] += lds[threadIdx.x + off];
        __syncthreads();
    }
    if (threadIdx.x == 0) out[0] = 1.f - lds[0] / (float)NPIX;
}

extern "C" void kernel_launch(void* const* d_in, const int* in_sizes, int n_in,
                              void* d_out, int out_size, void* d_ws, size_t ws_size,
                              hipStream_t stream) {
    const float* img1 = (const float*)d_in[0];
    const float* img2 = (const float*)d_in[1];
    float* out = (float*)d_out;
    float* partials = (float*)d_ws;

    dim3 grid(GX, GY, GZ);
    ssim_tile<<<grid, 512, 0, stream>>>(img1, img2, partials);
    ssim_reduce<<<1, 1024, 0, stream>>>(partials, out, NBLOCKS);
}

// Round 17
// 48.353 us; speedup vs baseline: 1.1575x; 1.0764x over previous
//
#include <hip/hip_runtime.h>
#include <hip/hip_fp16.h>

// SSIM loss — round 17: MFMA banded-conv, slim LDS + in-register q-fragments.
// vs r16: (1) only a,b f16 planes staged (q-fragments aa+bb / ab built in
// registers from a/b K-slices, 12 pk-f16 ops per tile); (2) sV 48-row stride,
// rows 42-47 zeroed -> v-reads are b128 and one A-band W[k-m] serves both
// v-tiles; (3) LDS 39.6KB -> 4 blocks/CU (32 waves, 100% ceiling).
// Phases: prep (420 balanced items) -> h-MFMA (48 tiles, 6/wave) ->
// v-MFMA (8 waves x 4 q) -> lane-local SSIM -> reduction.

#define IMGH 512
#define IMGW 512
#define TW 64
#define TH 32
#define GX 8
#define GY 16
#define GZ 48
#define NBLOCKS (GX * GY * GZ)   // 6144
#define NPIX (16 * 3 * 512 * 512)
#define C1F 1.0e-4f
#define C2F 9.0e-4f

#define INSTRIDE 88        // halfs/row (176B, 16B-aligned reads)
#define INPLANE (42 * INSTRIDE)       // 3696 halfs
#define VSTRIDE 48         // halfs/col (96B); rows 42..47 zero padding
#define VPLANE (64 * VSTRIDE)         // 3072 halfs
#define WBASE 34           // band center in sWext

// Gaussian weights, sigma=1.5, ws=11 (validated r1-r16).
#define W0 0.0010283818f
#define W1 0.0075987503f
#define W2 0.0360007547f
#define W3 0.1093606960f
#define W4 0.2130055367f
#define W5 0.2660117184f

typedef _Float16 half8v __attribute__((ext_vector_type(8)));
typedef float f32x4 __attribute__((ext_vector_type(4)));
union H8 { half8v v; __half2 h2[4]; float4 f4; };

static __device__ __forceinline__ __half2 pkrtz(float a, float b) {
    auto r = __builtin_amdgcn_cvt_pkrtz(a, b);   // __fp16 ext_vector(2)
    return *reinterpret_cast<__half2*>(&r);
}

__global__ __launch_bounds__(512, 8)
void ssim_tile(const float* __restrict__ img1, const float* __restrict__ img2,
               float* __restrict__ partials) {
    __shared__ _Float16 sWext[96];          // [WBASE..WBASE+10] = W[0..10]
    __shared__ _Float16 sIn[2 * INPLANE];   // 14,784 B : a | b
    __shared__ _Float16 sV[4 * VPLANE];     // 24,576 B : col-major, 48 rows
    __shared__ float wsum[8];

    const int tid  = threadIdx.x;
    const int lane = tid & 63;
    const int wv   = tid >> 6;
    const int r0 = blockIdx.y * TH;
    const int c0 = blockIdx.x * TW;
    const size_t pbase = (size_t)blockIdx.z * (IMGH * IMGW);
    const float* a0 = img1 + pbase;
    const float* b0 = img2 + pbase;
    const bool fast = (blockIdx.x >= 1) & (blockIdx.x <= GX - 2) &
                      (blockIdx.y >= 1) & (blockIdx.y <= GY - 2);

    // ---- weight table ----
    if (tid < 96) {
        const float W[11] = {W0, W1, W2, W3, W4, W5, W4, W3, W2, W1, W0};
        float w = 0.f;
#pragma unroll
        for (int j = 0; j < 11; ++j) w = (tid == WBASE + j) ? W[j] : w;
        sWext[tid] = (_Float16)w;
    }
    // ---- zero sV (pad rows must be 0, and avoids any stale reads) ----
    {
        const float4 z4 = make_float4(0.f, 0.f, 0.f, 0.f);
        float4* p = reinterpret_cast<float4*>(sV);
#pragma unroll
        for (int i = 0; i < 3; ++i) p[tid + (i << 9)] = z4;
    }
    // ---- prep: 420 items (42 rows x 10 8-col chunks), 1/thread ----
    if (tid < 420) {
        const int row = (unsigned)tid / 10u;
        const int ch  = tid - row * 10;
        const int gr = r0 - 5 + row;
        const int gc = c0 - 8 + 8 * ch;
        float4 va1 = make_float4(0.f, 0.f, 0.f, 0.f), va2 = va1;
        float4 vb1 = va1, vb2 = va1;
        if (fast || ((unsigned)gr < IMGH && (unsigned)gc < IMGW)) {
            const float* pa = a0 + (size_t)gr * IMGW + gc;
            const float* pb = b0 + (size_t)gr * IMGW + gc;
            va1 = *reinterpret_cast<const float4*>(pa);
            va2 = *reinterpret_cast<const float4*>(pa + 4);
            vb1 = *reinterpret_cast<const float4*>(pb);
            vb2 = *reinterpret_cast<const float4*>(pb + 4);
        }
        const int off = row * INSTRIDE + 8 * ch;
        H8 ha, hb;
        ha.h2[0] = pkrtz(va1.x, va1.y); ha.h2[1] = pkrtz(va1.z, va1.w);
        ha.h2[2] = pkrtz(va2.x, va2.y); ha.h2[3] = pkrtz(va2.z, va2.w);
        hb.h2[0] = pkrtz(vb1.x, vb1.y); hb.h2[1] = pkrtz(vb1.z, vb1.w);
        hb.h2[2] = pkrtz(vb2.x, vb2.y); hb.h2[3] = pkrtz(vb2.z, vb2.w);
        *reinterpret_cast<float4*>(&sIn[off]) = ha.f4;
        *reinterpret_cast<float4*>(&sIn[INPLANE + off]) = hb.f4;
    }
    __syncthreads();

    // ---- A fragments (guide m89 layout: M=lane&15, K=(lane>>4)*8+e) ----
    half8v Ah, Av;
    {
        const int bh = ((lane >> 4) << 3) - (lane & 15) - 3 + WBASE;  // W[k-m-3]
        const int bv = ((lane >> 4) << 3) - (lane & 15) + WBASE;      // W[k-m]
#pragma unroll
        for (int e = 0; e < 8; ++e) Ah[e] = sWext[bh + e];
#pragma unroll
        for (int e = 0; e < 8; ++e) Av[e] = sWext[bv + e];
    }

    // ---- h-phase: 48 tiles (rt,ct,q), 6 per wave ----
#pragma unroll
    for (int i = 0; i < 6; ++i) {
        const int id = wv * 6 + i;
        const int rt = id >> 4;
        const int ct = (id >> 2) & 3;
        const int q  = id & 3;
        const int rb = (rt == 0) ? 0 : (rt == 1 ? 16 : 26);
        const int row = rb + (lane & 15);              // h-row (N dim)
        const int base = row * INSTRIDE + 16 * ct + ((lane >> 4) << 3);
        H8 frag;
        if (q == 0) {
            frag.f4 = *reinterpret_cast<const float4*>(&sIn[base]);
        } else if (q == 1) {
            frag.f4 = *reinterpret_cast<const float4*>(&sIn[INPLANE + base]);
        } else {
            H8 fa, fb;
            fa.f4 = *reinterpret_cast<const float4*>(&sIn[base]);
            fb.f4 = *reinterpret_cast<const float4*>(&sIn[INPLANE + base]);
            if (q == 2) {
#pragma unroll
                for (int t = 0; t < 4; ++t)
                    frag.h2[t] = __hfma2(fa.h2[t], fa.h2[t],
                                         __hmul2(fb.h2[t], fb.h2[t]));
            } else {
#pragma unroll
                for (int t = 0; t < 4; ++t)
                    frag.h2[t] = __hmul2(fa.h2[t], fb.h2[t]);
            }
        }
        f32x4 d = {0.f, 0.f, 0.f, 0.f};
        d = __builtin_amdgcn_mfma_f32_16x16x32_f16(Ah, frag.v, d, 0, 0, 0);
        // store (rt1/rt2 overlap rows 26-31 write identical bits — benign)
#pragma unroll
        for (int j = 0; j < 4; ++j) {
            const int oc = 16 * ct + ((lane >> 4) << 2) + j;   // out col (M)
            sV[q * VPLANE + oc * VSTRIDE + row] = (_Float16)d[j];
        }
    }
    __syncthreads();

    // ---- v-phase: wave wv owns (rt2, ct2); 4 MFMA, b128 reads ----
    const int rt2 = wv >> 2;
    const int ct2 = wv & 3;
    const int vcol = 16 * ct2 + (lane & 15);           // out col (N)
    const int rowst = (rt2 ? 16 : 0) + ((lane >> 4) << 3);
    const int vbase = vcol * VSTRIDE + rowst;
    auto vread = [&](int q) -> half8v {
        H8 c;
        c.f4 = *reinterpret_cast<const float4*>(&sV[q * VPLANE + vbase]);
        return c.v;
    };
    f32x4 d0 = {0.f, 0.f, 0.f, 0.f}, d1 = d0, d2 = d0, d3 = d0;
    d0 = __builtin_amdgcn_mfma_f32_16x16x32_f16(Av, vread(0), d0, 0, 0, 0);
    d1 = __builtin_amdgcn_mfma_f32_16x16x32_f16(Av, vread(1), d1, 0, 0, 0);
    d2 = __builtin_amdgcn_mfma_f32_16x16x32_f16(Av, vread(2), d2, 0, 0, 0);
    d3 = __builtin_amdgcn_mfma_f32_16x16x32_f16(Av, vread(3), d3, 0, 0, 0);

    // ---- SSIM map, lane-local on f32 conv outputs ----
    float lsum = 0.f;
#pragma unroll
    for (int r = 0; r < 4; ++r) {
        const float mu1 = d0[r], mu2 = d1[r], S = d2[r], eab = d3[r];
        const float mu11 = mu1 * mu1, mu22 = mu2 * mu2, mu12 = mu1 * mu2;
        const float s12 = eab - mu12;
        const float num = (2.f * mu12 + C1F) * (2.f * s12 + C2F);
        const float den = (mu11 + mu22 + C1F) * ((S - mu11 - mu22) + C2F);
        lsum += num * __builtin_amdgcn_rcpf(den);
    }

    // ---- deterministic block reduction (8 waves) ----
#pragma unroll
    for (int off = 32; off > 0; off >>= 1) lsum += __shfl_down(lsum, off, 64);
    if (lane == 0) wsum[wv] = lsum;
    __syncthreads();
    if (tid == 0) {
        float t = 0.f;
#pragma unroll
        for (int w = 0; w < 8; ++w) t += wsum[w];
        partials[((size_t)blockIdx.z * GY + blockIdx.y) * GX + blockIdx.x] = t;
    }
}

__global__ __launch_bounds__(1024)
void ssim_reduce(const float* __restrict__ partials, float* __restrict__ out, int n) {
    __shared__ float lds[1024];
    float s = 0.f;
    for (int i = threadIdx.x; i < n; i += 1024) s += partials[i];
    lds[threadIdx.x] = s;
    __syncthreads();
    for (int off = 512; off > 0; off >>= 1) {
        if ((int)threadIdx.x < off) lds[threadIdx.x] += lds[threadIdx.x + off];
        __syncthreads();
    }
    if (threadIdx.x == 0) out[0] = 1.f - lds[0] / (float)NPIX;
}

extern "C" void kernel_launch(void* const* d_in, const int* in_sizes, int n_in,
                              void* d_out, int out_size, void* d_ws, size_t ws_size,
                              hipStream_t stream) {
    const float* img1 = (const float*)d_in[0];
    const float* img2 = (const float*)d_in[1];
    float* out = (float*)d_out;
    float* partials = (float*)d_ws;

    dim3 grid(GX, GY, GZ);
    ssim_tile<<<grid, 512, 0, stream>>>(img1, img2, partials);
    ssim_reduce<<<1, 1024, 0, stream>>>(partials, out, NBLOCKS);
}

// Round 18
// 47.392 us; speedup vs baseline: 1.1810x; 1.0203x over previous
//
#include <hip/hip_runtime.h>
#include <hip/hip_fp16.h>

// SSIM loss — round 18: r17 slim-LDS MFMA conv + r16's conflict-free sV.
// vs r17: (1) sV back to VSTRIDE=44 col-major (h-store lane-groups land on
// disjoint bank quartets: 4col x 88B = 88 words == 24 mod 32), v-reads via
// 4 x b32 (2 lanes/bank = free), two Av bands (windows 0 / 10) -> rows
// 0..41 only, NO zero pass; (2) prep fast/slow hoisted. LDS 37.5KB,
// 4 blocks/CU. Phases: prep(420) -> h-MFMA(48) -> v-MFMA(32) -> SSIM.

#define IMGH 512
#define IMGW 512
#define TW 64
#define TH 32
#define GX 8
#define GY 16
#define GZ 48
#define NBLOCKS (GX * GY * GZ)   // 6144
#define NPIX (16 * 3 * 512 * 512)
#define C1F 1.0e-4f
#define C2F 9.0e-4f

#define INSTRIDE 88        // halfs/row (176B, 16B-aligned b128 reads)
#define INPLANE (42 * INSTRIDE)       // 3696 halfs
#define VSTRIDE 44         // halfs/col (88B) -> conflict-free stores/reads
#define VPLANE (64 * VSTRIDE)         // 2816 halfs
#define WBASE 34           // band center in sWext

// Gaussian weights, sigma=1.5, ws=11 (validated r1-r17).
#define W0 0.0010283818f
#define W1 0.0075987503f
#define W2 0.0360007547f
#define W3 0.1093606960f
#define W4 0.2130055367f
#define W5 0.2660117184f

typedef _Float16 half8v __attribute__((ext_vector_type(8)));
typedef float f32x4 __attribute__((ext_vector_type(4)));
union H8 { half8v v; __half2 h2[4]; float4 f4; unsigned u[4]; };

static __device__ __forceinline__ __half2 pkrtz(float a, float b) {
    auto r = __builtin_amdgcn_cvt_pkrtz(a, b);   // __fp16 ext_vector(2)
    return *reinterpret_cast<__half2*>(&r);
}

__global__ __launch_bounds__(512, 8)
void ssim_tile(const float* __restrict__ img1, const float* __restrict__ img2,
               float* __restrict__ partials) {
    __shared__ _Float16 sWext[96];          // [WBASE..WBASE+10] = W[0..10]
    __shared__ _Float16 sIn[2 * INPLANE];   // 14,784 B : a | b
    __shared__ _Float16 sV[4 * VPLANE];     // 22,528 B : col-major, 44 rows
    __shared__ float wsum[8];

    const int tid  = threadIdx.x;
    const int lane = tid & 63;
    const int wv   = tid >> 6;
    const int r0 = blockIdx.y * TH;
    const int c0 = blockIdx.x * TW;
    const size_t pbase = (size_t)blockIdx.z * (IMGH * IMGW);
    const float* a0 = img1 + pbase;
    const float* b0 = img2 + pbase;
    const bool fast = (blockIdx.x >= 1) & (blockIdx.x <= GX - 2) &
                      (blockIdx.y >= 1) & (blockIdx.y <= GY - 2);

    // ---- weight table ----
    if (tid < 96) {
        const float W[11] = {W0, W1, W2, W3, W4, W5, W4, W3, W2, W1, W0};
        float w = 0.f;
#pragma unroll
        for (int j = 0; j < 11; ++j) w = (tid == WBASE + j) ? W[j] : w;
        sWext[tid] = (_Float16)w;
    }

    // ---- prep: 420 items (42 rows x 10 8-col chunks), 1/thread ----
    if (tid < 420) {
        const int row = (unsigned)tid / 10u;
        const int ch  = tid - row * 10;
        const int gr = r0 - 5 + row;
        const int gc = c0 - 8 + 8 * ch;
        float4 va1, va2, vb1, vb2;
        if (fast) {
            const float* pa = a0 + (size_t)gr * IMGW + gc;
            const float* pb = b0 + (size_t)gr * IMGW + gc;
            va1 = *reinterpret_cast<const float4*>(pa);
            va2 = *reinterpret_cast<const float4*>(pa + 4);
            vb1 = *reinterpret_cast<const float4*>(pb);
            vb2 = *reinterpret_cast<const float4*>(pb + 4);
        } else {
            va1 = make_float4(0.f, 0.f, 0.f, 0.f);
            va2 = vb1 = vb2 = va1;
            if ((unsigned)gr < IMGH && (unsigned)gc < IMGW) {
                const float* pa = a0 + (size_t)gr * IMGW + gc;
                const float* pb = b0 + (size_t)gr * IMGW + gc;
                va1 = *reinterpret_cast<const float4*>(pa);
                va2 = *reinterpret_cast<const float4*>(pa + 4);
                vb1 = *reinterpret_cast<const float4*>(pb);
                vb2 = *reinterpret_cast<const float4*>(pb + 4);
            }
        }
        const int off = row * INSTRIDE + 8 * ch;
        H8 ha, hb;
        ha.h2[0] = pkrtz(va1.x, va1.y); ha.h2[1] = pkrtz(va1.z, va1.w);
        ha.h2[2] = pkrtz(va2.x, va2.y); ha.h2[3] = pkrtz(va2.z, va2.w);
        hb.h2[0] = pkrtz(vb1.x, vb1.y); hb.h2[1] = pkrtz(vb1.z, vb1.w);
        hb.h2[2] = pkrtz(vb2.x, vb2.y); hb.h2[3] = pkrtz(vb2.z, vb2.w);
        *reinterpret_cast<float4*>(&sIn[off]) = ha.f4;
        *reinterpret_cast<float4*>(&sIn[INPLANE + off]) = hb.f4;
    }
    __syncthreads();

    // ---- A fragments (guide m89 layout: M=lane&15, K=(lane>>4)*8+e) ----
    const int rt2 = wv >> 2;                   // this wave's v row-tile
    half8v Ah, Av;
    {
        const int bh = ((lane >> 4) << 3) - (lane & 15) - 3 + WBASE;  // W[k-m-3]
        const int bv = ((lane >> 4) << 3) - (lane & 15) - (rt2 ? 6 : 0) + WBASE;
#pragma unroll
        for (int e = 0; e < 8; ++e) Ah[e] = sWext[bh + e];
#pragma unroll
        for (int e = 0; e < 8; ++e) Av[e] = sWext[bv + e];
    }

    // ---- h-phase: 48 tiles (rt,ct,q), 6 per wave ----
#pragma unroll
    for (int i = 0; i < 6; ++i) {
        const int id = wv * 6 + i;
        const int rt = id >> 4;
        const int ct = (id >> 2) & 3;
        const int q  = id & 3;
        const int rb = (rt == 0) ? 0 : (rt == 1 ? 16 : 26);
        const int row = rb + (lane & 15);              // h-row (N dim)
        const int base = row * INSTRIDE + 16 * ct + ((lane >> 4) << 3);
        H8 frag;
        if (q == 0) {
            frag.f4 = *reinterpret_cast<const float4*>(&sIn[base]);
        } else if (q == 1) {
            frag.f4 = *reinterpret_cast<const float4*>(&sIn[INPLANE + base]);
        } else {
            H8 fa, fb;
            fa.f4 = *reinterpret_cast<const float4*>(&sIn[base]);
            fb.f4 = *reinterpret_cast<const float4*>(&sIn[INPLANE + base]);
            if (q == 2) {
#pragma unroll
                for (int t = 0; t < 4; ++t)
                    frag.h2[t] = __hfma2(fa.h2[t], fa.h2[t],
                                         __hmul2(fb.h2[t], fb.h2[t]));
            } else {
#pragma unroll
                for (int t = 0; t < 4; ++t)
                    frag.h2[t] = __hmul2(fa.h2[t], fb.h2[t]);
            }
        }
        f32x4 d = {0.f, 0.f, 0.f, 0.f};
        d = __builtin_amdgcn_mfma_f32_16x16x32_f16(Ah, frag.v, d, 0, 0, 0);
        // rt=1/rt=2 overlap rows 26-31: identical bits — benign.
#pragma unroll
        for (int j = 0; j < 4; ++j) {
            const int oc = 16 * ct + ((lane >> 4) << 2) + j;   // out col (M)
            sV[q * VPLANE + oc * VSTRIDE + row] = (_Float16)d[j];
        }
    }
    __syncthreads();

    // ---- v-phase: wave wv owns (rt2, ct2); windows {0,10}, 4 x b32 reads ----
    const int ct2 = wv & 3;
    const int w0 = rt2 ? 10 : 0;
    const int vcol = 16 * ct2 + (lane & 15);           // out col (N)
    const int rowst = w0 + ((lane >> 4) << 3);         // K chunk start
    const int vbase = vcol * VSTRIDE + rowst;
    auto vread = [&](int q) -> half8v {
        const _Float16* p = &sV[q * VPLANE + vbase];
        H8 c;
        c.u[0] = *reinterpret_cast<const unsigned*>(p);
        c.u[1] = *reinterpret_cast<const unsigned*>(p + 2);
        c.u[2] = *reinterpret_cast<const unsigned*>(p + 4);
        c.u[3] = *reinterpret_cast<const unsigned*>(p + 6);
        return c.v;
    };
    f32x4 d0 = {0.f, 0.f, 0.f, 0.f}, d1 = d0, d2 = d0, d3 = d0;
    d0 = __builtin_amdgcn_mfma_f32_16x16x32_f16(Av, vread(0), d0, 0, 0, 0);
    d1 = __builtin_amdgcn_mfma_f32_16x16x32_f16(Av, vread(1), d1, 0, 0, 0);
    d2 = __builtin_amdgcn_mfma_f32_16x16x32_f16(Av, vread(2), d2, 0, 0, 0);
    d3 = __builtin_amdgcn_mfma_f32_16x16x32_f16(Av, vread(3), d3, 0, 0, 0);

    // ---- SSIM map, lane-local on f32 conv outputs ----
    float lsum = 0.f;
#pragma unroll
    for (int r = 0; r < 4; ++r) {
        const float mu1 = d0[r], mu2 = d1[r], S = d2[r], eab = d3[r];
        const float mu11 = mu1 * mu1, mu22 = mu2 * mu2, mu12 = mu1 * mu2;
        const float s12 = eab - mu12;
        const float num = (2.f * mu12 + C1F) * (2.f * s12 + C2F);
        const float den = (mu11 + mu22 + C1F) * ((S - mu11 - mu22) + C2F);
        lsum += num * __builtin_amdgcn_rcpf(den);
    }

    // ---- deterministic block reduction (8 waves) ----
#pragma unroll
    for (int off = 32; off > 0; off >>= 1) lsum += __shfl_down(lsum, off, 64);
    if (lane == 0) wsum[wv] = lsum;
    __syncthreads();
    if (tid == 0) {
        float t = 0.f;
#pragma unroll
        for (int w = 0; w < 8; ++w) t += wsum[w];
        partials[((size_t)blockIdx.z * GY + blockIdx.y) * GX + blockIdx.x] = t;
    }
}

__global__ __launch_bounds__(1024)
void ssim_reduce(const float* __restrict__ partials, float* __restrict__ out, int n) {
    __shared__ float lds[1024];
    float s = 0.f;
    for (int i = threadIdx.x; i < n; i += 1024) s += partials[i];
    lds[threadIdx.x] = s;
    __syncthreads();
    for (int off = 512; off > 0; off >>= 1) {
        if ((int)threadIdx.x < off) lds[threadIdx.x] += lds[threadIdx.x + off];
        __syncthreads();
    }
    if (threadIdx.x == 0) out[0] = 1.f - lds[0] / (float)NPIX;
}

extern "C" void kernel_launch(void* const* d_in, const int* in_sizes, int n_in,
                              void* d_out, int out_size, void* d_ws, size_t ws_size,
                              hipStream_t stream) {
    const float* img1 = (const float*)d_in[0];
    const float* img2 = (const float*)d_in[1];
    float* out = (float*)d_out;
    float* partials = (float*)d_ws;

    dim3 grid(GX, GY, GZ);
    ssim_tile<<<grid, 512, 0, stream>>>(img1, img2, partials);
    ssim_reduce<<<1, 1024, 0, stream>>>(partials, out, NBLOCKS);
}